// Round 1
// baseline (4031.436 us; speedup 1.0000x reference)
//
#include <hip/hip_runtime.h>
#include <hip/hip_bf16.h>

#define NN 8192
#define FIN 256
#define FOUT 64

typedef __attribute__((ext_vector_type(8))) short short8;
typedef __attribute__((ext_vector_type(4))) float f32x4;

__device__ __forceinline__ unsigned short f2bf(float x){
  unsigned u = __float_as_uint(x);
  u += 0x7FFFu + ((u >> 16) & 1u);      // RTNE
  return (unsigned short)(u >> 16);
}

// k1: Wh = h@W in fp32; f_src/f_dst in fp32; WhT (bf16, [64][8192]) for MFMA B;
// global max of f_dst via uint atomicMax on (f_dst+64.0) bits (monotone for >0).
__global__ __launch_bounds__(256) void k_prep(const float* __restrict__ h,
    const float* __restrict__ W, const float* __restrict__ a,
    unsigned short* __restrict__ WhT, float* __restrict__ fs,
    float* __restrict__ fd, unsigned* __restrict__ gmax_u){
  __shared__ float Ws[128*64];   // 32 KB: half of W (k-tiled)
  __shared__ float hs[8][128];   // 4 KB: 8 rows, k-half
  const int t = threadIdx.x, l = t & 63, wv = t >> 6;
  const int rb = blockIdx.x * 8;            // 8 rows per block, 2 per wave
  float acc0 = 0.f, acc1 = 0.f;
  for (int half = 0; half < 2; ++half){
    if (half) __syncthreads();
    for (int i = t; i < 2048; i += 256)
      ((float4*)Ws)[i] = ((const float4*)W)[half*2048 + i];
    {
      int rr = t >> 5, cc = t & 31;
      ((float4*)&hs[rr][0])[cc] =
          *(const float4*)(h + (size_t)(rb+rr)*FIN + half*128 + cc*4);
    }
    __syncthreads();
    #pragma unroll 8
    for (int k = 0; k < 128; ++k){
      float wval = Ws[k*64 + l];             // lane l = output feature
      acc0 = fmaf(hs[wv*2+0][k], wval, acc0);
      acc1 = fmaf(hs[wv*2+1][k], wval, acc1);
    }
  }
  const int r0 = rb + wv*2, r1 = r0 + 1;
  float a1 = a[l], a2 = a[64 + l];
  float p0 = acc0*a1, q0 = acc0*a2, p1 = acc1*a1, q1 = acc1*a2;
  #pragma unroll
  for (int m = 1; m < 64; m <<= 1){
    p0 += __shfl_xor(p0, m); q0 += __shfl_xor(q0, m);
    p1 += __shfl_xor(p1, m); q1 += __shfl_xor(q1, m);
  }
  if (l == 0){
    fs[r0] = p0; fs[r1] = p1; fd[r0] = q0; fd[r1] = q1;
    atomicMax(gmax_u, __float_as_uint(q0 + 64.0f));
    atomicMax(gmax_u, __float_as_uint(q1 + 64.0f));
  }
  WhT[(size_t)l*NN + r0] = f2bf(acc0);
  WhT[(size_t)l*NN + r1] = f2bf(acc1);
}

// k2: per wave: 16-row i-tile, split-K chunk of 2048 j's, 64 K-steps of 32.
// A-frag = P tile built in registers (adj mask + exp), B-frag = WhT from L2.
// Verified layouts (m89/m120): A[m=lane&15][k=(lane>>4)*8+j],
// B[k=(lane>>4)*8+j][n=lane&15], C col=lane&15 row=(lane>>4)*4+reg.
__global__ __launch_bounds__(256, 2) void k_attn(const int* __restrict__ adj,
    const unsigned short* __restrict__ WhT, const float* __restrict__ fs,
    const float* __restrict__ fd, const unsigned* __restrict__ gmax_u,
    float* __restrict__ acc_out, float* __restrict__ s_out){
  const int l = threadIdx.x & 63;
  const int task = blockIdx.x*4 + (threadIdx.x >> 6);  // 2048 wave-tasks
  const int itile = task & 511, kchunk = task >> 9;    // 512 i-tiles x 4 splits
  const int ibase = itile*16, row = l & 15, quad = l >> 4;
  const float gmax = __uint_as_float(*gmax_u) - 64.0f;
  const float fsr  = fs[ibase + row];
  const float x0   = fsr + gmax;
  const float mrow = fmaxf(x0, 0.2f*x0);   // upper bound of row max (leaky monotone)

  const size_t koff = (size_t)kchunk*2048 + quad*8;
  const int*            ap = adj + (size_t)(ibase+row)*NN + koff;
  const float*          fp = fd + koff;
  const unsigned short* wp = WhT + (size_t)row*NN + koff;

  f32x4 acc[4]; 
  #pragma unroll
  for (int nb = 0; nb < 4; ++nb) acc[nb] = (f32x4){0.f,0.f,0.f,0.f};

  int4 A0[2], A1[2]; float4 F0[2], F1[2]; short8 Bf[2][4];
  auto load = [&](int s, int b){
    const int* aps = ap + s*32;
    A0[b] = *(const int4*)aps; A1[b] = *(const int4*)(aps + 4);
    const float* fps = fp + s*32;
    F0[b] = *(const float4*)fps; F1[b] = *(const float4*)(fps + 4);
    #pragma unroll
    for (int nb = 0; nb < 4; ++nb)
      Bf[b][nb] = *(const short8*)(wp + nb*(16*NN) + s*32);
  };

  float sacc = 0.f;
  load(0, 0);
  for (int s = 0; s < 64; ++s){
    const int b = s & 1;
    if (s < 63) load(s + 1, b ^ 1);         // prefetch next step (MLP)
    int   av[8] = {A0[b].x,A0[b].y,A0[b].z,A0[b].w, A1[b].x,A1[b].y,A1[b].z,A1[b].w};
    float fv[8] = {F0[b].x,F0[b].y,F0[b].z,F0[b].w, F1[b].x,F1[b].y,F1[b].z,F1[b].w};
    short8 af;
    #pragma unroll
    for (int j = 0; j < 8; ++j){
      float x  = fsr + fv[j];
      float tt = fmaxf(x, 0.2f*x);          // leaky_relu
      float w  = __expf(tt - mrow);         // v_exp_f32 path
      w = (av[j] != 0) ? w : 0.0f;          // adj mask
      sacc += w;
      af[j] = (short)f2bf(w);
    }
    #pragma unroll
    for (int nb = 0; nb < 4; ++nb)
      acc[nb] = __builtin_amdgcn_mfma_f32_16x16x32_bf16(af, Bf[b][nb], acc[nb], 0, 0, 0);
  }
  // row-sum: lane covers row=l&15, k-quarter quad -> reduce across quads
  sacc += __shfl_xor(sacc, 16);
  sacc += __shfl_xor(sacc, 32);
  if (l < 16) s_out[kchunk*NN + ibase + l] = sacc;
  float* op = acc_out + ((size_t)kchunk*NN + ibase)*FOUT;
  #pragma unroll
  for (int nb = 0; nb < 4; ++nb)
    #pragma unroll
    for (int r = 0; r < 4; ++r)
      op[(quad*4 + r)*FOUT + nb*16 + row] = acc[nb][r];
}

// k3: combine split-K partials, normalize, ELU, write fp32 out.
__global__ __launch_bounds__(256) void k_out(const float* __restrict__ acc,
    const float* __restrict__ s, float* __restrict__ out){
  const int idx = blockIdx.x*256 + threadIdx.x;   // 524288 total
  const int i = idx >> 6;
  float num = acc[idx] + acc[idx + NN*FOUT] + acc[idx + 2*NN*FOUT] + acc[idx + 3*NN*FOUT];
  float den = s[i] + s[i + NN] + s[i + 2*NN] + s[i + 3*NN];
  float x = num / den;
  out[idx] = (x > 0.f) ? x : (__expf(x) - 1.0f);
}

extern "C" void kernel_launch(void* const* d_in, const int* in_sizes, int n_in,
                              void* d_out, int out_size, void* d_ws, size_t ws_size,
                              hipStream_t stream){
  const float* h   = (const float*)d_in[0];
  const int*   adj = (const int*)d_in[1];
  const float* W   = (const float*)d_in[2];
  const float* a   = (const float*)d_in[3];
  char* ws = (char*)d_ws;
  // ws layout: [0,1MB) WhT bf16 | fs 32KB | fd 32KB | gmax 4B | [2MB,10MB) acc | s 128KB
  unsigned short* WhT = (unsigned short*)ws;
  float*    fs     = (float*)(ws + (1u<<20));
  float*    fd     = (float*)(ws + (1u<<20) + 32768);
  unsigned* gmax_u = (unsigned*)(ws + (1u<<20) + 65536);
  float*    acc    = (float*)(ws + (2u<<20));
  float*    s_ws   = (float*)(ws + (2u<<20) + (size_t)4*NN*FOUT*4);

  hipMemsetAsync(gmax_u, 0, 4, stream);
  k_prep<<<1024, 256, 0, stream>>>(h, W, a, WhT, fs, fd, gmax_u);
  k_attn<<<512, 256, 0, stream>>>(adj, WhT, fs, fd, gmax_u, acc, s_ws);
  k_out<<<2048, 256, 0, stream>>>(acc, s_ws, (float*)d_out);
}

// Round 3
// 526.520 us; speedup vs baseline: 7.6568x; 7.6568x over previous
//
#include <hip/hip_runtime.h>
#include <hip/hip_bf16.h>

#define NN 8192
#define FIN 256
#define FOUT 64

typedef __attribute__((ext_vector_type(8))) short short8;
typedef __attribute__((ext_vector_type(4))) float f32x4;
typedef __attribute__((ext_vector_type(4))) int   iv4;

__device__ __forceinline__ unsigned short f2bf(float x){
  unsigned u = __float_as_uint(x);
  u += 0x7FFFu + ((u >> 16) & 1u);      // RTNE
  return (unsigned short)(u >> 16);
}

// k1: Wh = h@W in fp32; f_src/f_dst in fp32; WhT (bf16, [64][8192]) for MFMA B;
// global max of f_dst via uint atomicMax on (f_dst+64.0) bits (monotone for >0).
__global__ __launch_bounds__(256) void k_prep(const float* __restrict__ h,
    const float* __restrict__ W, const float* __restrict__ a,
    unsigned short* __restrict__ WhT, float* __restrict__ fs,
    float* __restrict__ fd, unsigned* __restrict__ gmax_u){
  __shared__ float Ws[128*64];   // 32 KB: half of W (k-tiled)
  __shared__ float hs[8][128];   // 4 KB: 8 rows, k-half
  const int t = threadIdx.x, l = t & 63, wv = t >> 6;
  const int rb = blockIdx.x * 8;            // 8 rows per block, 2 per wave
  float acc0 = 0.f, acc1 = 0.f;
  for (int half = 0; half < 2; ++half){
    if (half) __syncthreads();
    for (int i = t; i < 2048; i += 256)
      ((float4*)Ws)[i] = ((const float4*)W)[half*2048 + i];
    {
      int rr = t >> 5, cc = t & 31;
      ((float4*)&hs[rr][0])[cc] =
          *(const float4*)(h + (size_t)(rb+rr)*FIN + half*128 + cc*4);
    }
    __syncthreads();
    #pragma unroll 8
    for (int k = 0; k < 128; ++k){
      float wval = Ws[k*64 + l];             // lane l = output feature
      acc0 = fmaf(hs[wv*2+0][k], wval, acc0);
      acc1 = fmaf(hs[wv*2+1][k], wval, acc1);
    }
  }
  const int r0 = rb + wv*2, r1 = r0 + 1;
  float a1 = a[l], a2 = a[64 + l];
  float p0 = acc0*a1, q0 = acc0*a2, p1 = acc1*a1, q1 = acc1*a2;
  #pragma unroll
  for (int m = 1; m < 64; m <<= 1){
    p0 += __shfl_xor(p0, m); q0 += __shfl_xor(q0, m);
    p1 += __shfl_xor(p1, m); q1 += __shfl_xor(q1, m);
  }
  if (l == 0){
    fs[r0] = p0; fs[r1] = p1; fd[r0] = q0; fd[r1] = q1;
    atomicMax(gmax_u, __float_as_uint(q0 + 64.0f));
    atomicMax(gmax_u, __float_as_uint(q1 + 64.0f));
  }
  WhT[(size_t)l*NN + r0] = f2bf(acc0);
  WhT[(size_t)l*NN + r1] = f2bf(acc1);
}

// ---- k_attn: per wave: 16-row i-tile, split-K chunk of 2048 j's, 64 steps of 32.
// All prefetch buffers are NAMED members indexed statically -> no scratch demotion.
struct Buf {
  iv4    a0, a1;   // adj, 8 ints
  float4 f0, f1;   // f_dst, 8 floats
  short8 w0, w1, w2, w3;  // WhT B-frags for the 4 n-blocks
};

__device__ __forceinline__ void load_buf(Buf& b, const int* ap, const float* fp,
                                         const unsigned short* wp, int s){
  const int* aps = ap + s*32;
  b.a0 = __builtin_nontemporal_load((const iv4*)aps);
  b.a1 = __builtin_nontemporal_load(((const iv4*)aps) + 1);
  const float* fps = fp + s*32;
  b.f0 = *(const float4*)fps;
  b.f1 = *(const float4*)(fps + 4);
  const unsigned short* wps = wp + s*32;
  b.w0 = *(const short8*)(wps);
  b.w1 = *(const short8*)(wps + 16*NN);
  b.w2 = *(const short8*)(wps + 32*NN);
  b.w3 = *(const short8*)(wps + 48*NN);
}

__device__ __forceinline__ void step_buf(const Buf& b, float fsr, float mrow,
                                         f32x4* acc, float& sacc){
  const int   av[8] = {b.a0.x,b.a0.y,b.a0.z,b.a0.w, b.a1.x,b.a1.y,b.a1.z,b.a1.w};
  const float fv[8] = {b.f0.x,b.f0.y,b.f0.z,b.f0.w, b.f1.x,b.f1.y,b.f1.z,b.f1.w};
  float w[8];
  #pragma unroll
  for (int j = 0; j < 8; ++j){
    float x  = fsr + fv[j];
    float tt = fmaxf(x, 0.2f*x);          // leaky_relu
    float e  = __expf(tt - mrow);
    w[j] = (av[j] != 0) ? e : 0.0f;       // adj mask
    sacc += w[j];
  }
  short8 af;
  __hip_bfloat162* afp = (__hip_bfloat162*)&af;
  #pragma unroll
  for (int j = 0; j < 4; ++j)
    afp[j] = __float22bfloat162_rn(make_float2(w[2*j], w[2*j+1]));  // v_cvt_pk_bf16_f32
  acc[0] = __builtin_amdgcn_mfma_f32_16x16x32_bf16(af, b.w0, acc[0], 0,0,0);
  acc[1] = __builtin_amdgcn_mfma_f32_16x16x32_bf16(af, b.w1, acc[1], 0,0,0);
  acc[2] = __builtin_amdgcn_mfma_f32_16x16x32_bf16(af, b.w2, acc[2], 0,0,0);
  acc[3] = __builtin_amdgcn_mfma_f32_16x16x32_bf16(af, b.w3, acc[3], 0,0,0);
}

// Verified layouts (m89/m120): A[m=lane&15][k=(lane>>4)*8+j],
// B[k=(lane>>4)*8+j][n=lane&15], C col=lane&15 row=(lane>>4)*4+reg.
__global__ __launch_bounds__(256, 2) void k_attn(const int* __restrict__ adj,
    const unsigned short* __restrict__ WhT, const float* __restrict__ fs,
    const float* __restrict__ fd, const unsigned* __restrict__ gmax_u,
    float* __restrict__ acc_out, float* __restrict__ s_out){
  const int l = threadIdx.x & 63;
  const int task = blockIdx.x*4 + (threadIdx.x >> 6);  // 2048 wave-tasks
  const int itile = task & 511, kchunk = task >> 9;    // 512 i-tiles x 4 splits
  const int ibase = itile*16, row = l & 15, quad = l >> 4;
  const float gmax = __uint_as_float(*gmax_u) - 64.0f;
  const float fsr  = fs[ibase + row];
  const float x0   = fsr + gmax;
  const float mrow = fmaxf(x0, 0.2f*x0);   // upper bound of row max (leaky monotone)

  const size_t koff = (size_t)kchunk*2048 + quad*8;
  const int*            ap = adj + (size_t)(ibase+row)*NN + koff;
  const float*          fp = fd + koff;
  const unsigned short* wp = WhT + (size_t)row*NN + koff;

  f32x4 acc[4];
  #pragma unroll
  for (int nb = 0; nb < 4; ++nb) acc[nb] = (f32x4){0.f,0.f,0.f,0.f};

  Buf b0, b1, b2, b3;
  load_buf(b0, ap, fp, wp, 0);
  load_buf(b1, ap, fp, wp, 1);
  load_buf(b2, ap, fp, wp, 2);
  load_buf(b3, ap, fp, wp, 3);

  float sacc = 0.f;
  #pragma unroll 1
  for (int s = 0; s < 64; s += 4){
    step_buf(b0, fsr, mrow, acc, sacc); if (s+4 < 64) load_buf(b0, ap, fp, wp, s+4);
    step_buf(b1, fsr, mrow, acc, sacc); if (s+5 < 64) load_buf(b1, ap, fp, wp, s+5);
    step_buf(b2, fsr, mrow, acc, sacc); if (s+6 < 64) load_buf(b2, ap, fp, wp, s+6);
    step_buf(b3, fsr, mrow, acc, sacc); if (s+7 < 64) load_buf(b3, ap, fp, wp, s+7);
  }

  // row-sum: lane covers row=l&15, k-quarter quad -> reduce across quads
  sacc += __shfl_xor(sacc, 16);
  sacc += __shfl_xor(sacc, 32);
  if (l < 16) s_out[kchunk*NN + ibase + l] = sacc;
  float* op = acc_out + ((size_t)kchunk*NN + ibase)*FOUT;
  #pragma unroll
  for (int nb = 0; nb < 4; ++nb)
    #pragma unroll
    for (int r = 0; r < 4; ++r)
      op[(quad*4 + r)*FOUT + nb*16 + row] = acc[nb][r];
}

// k3: combine split-K partials, normalize, ELU, write fp32 out.
__global__ __launch_bounds__(256) void k_out(const float* __restrict__ acc,
    const float* __restrict__ s, float* __restrict__ out){
  const int idx = blockIdx.x*256 + threadIdx.x;   // 524288 total
  const int i = idx >> 6;
  float num = acc[idx] + acc[idx + NN*FOUT] + acc[idx + 2*NN*FOUT] + acc[idx + 3*NN*FOUT];
  float den = s[i] + s[i + NN] + s[i + 2*NN] + s[i + 3*NN];
  float x = num / den;
  out[idx] = (x > 0.f) ? x : (__expf(x) - 1.0f);
}

extern "C" void kernel_launch(void* const* d_in, const int* in_sizes, int n_in,
                              void* d_out, int out_size, void* d_ws, size_t ws_size,
                              hipStream_t stream){
  const float* h   = (const float*)d_in[0];
  const int*   adj = (const int*)d_in[1];
  const float* W   = (const float*)d_in[2];
  const float* a   = (const float*)d_in[3];
  char* ws = (char*)d_ws;
  // ws layout: [0,1MB) WhT bf16 | fs 32KB | fd 32KB | gmax 4B | [2MB,10MB) acc | s 128KB
  unsigned short* WhT = (unsigned short*)ws;
  float*    fs     = (float*)(ws + (1u<<20));
  float*    fd     = (float*)(ws + (1u<<20) + 32768);
  unsigned* gmax_u = (unsigned*)(ws + (1u<<20) + 65536);
  float*    acc    = (float*)(ws + (2u<<20));
  float*    s_ws   = (float*)(ws + (2u<<20) + (size_t)4*NN*FOUT*4);

  (void)hipMemsetAsync(gmax_u, 0, 4, stream);
  k_prep<<<1024, 256, 0, stream>>>(h, W, a, WhT, fs, fd, gmax_u);
  k_attn<<<512, 256, 0, stream>>>(adj, WhT, fs, fd, gmax_u, acc, s_ws);
  k_out<<<2048, 256, 0, stream>>>(acc, s_ws, (float*)d_out);
}